// Round 4
// baseline (1237.940 us; speedup 1.0000x reference)
//
#include <hip/hip_runtime.h>
#include <math.h>

// B=64, T=1000, S=96, A=32, INP=128, H=256. All I/O fp32.
// d_ws layout:
//   pre_perm fp16 [8000 slabs][256 tid][16 v] = 65,536,000 B   (slab=(br*4+G)*1000+t)
//   h_perm   fp16 same layout               = 65,536,000 B
//   G3 f16 W_hh B-frag table (262,144 B) at d_ws+130,416,640  (tail of h region)
//   G1/G2 bf16 frag tables  (393,216 B) at d_ws+130,678,784  (tail of h region)
// Tail tables are consumed at ff/rnn START; rnn's h writes only reach those
// bytes at t>=920 of slab-group (br=1,G=3) — hundreds of µs later.
// Permuted value layout: for (br, b, t, n):  G=b>>4, g2=(b>>2)&3, rr=b&3,
//   wv=n>>6, tl=(n>>4)&3, m=n&15; tid=wv*64+g2*16+m; v=rr*4+tl.

typedef _Float16 half2_t __attribute__((ext_vector_type(2)));
typedef _Float16 f16x8   __attribute__((ext_vector_type(8)));    // 4 VGPRs
typedef _Float16 f16x16  __attribute__((ext_vector_type(16)));   // 8 VGPRs
typedef __attribute__((ext_vector_type(8))) short bf16x8;
typedef __attribute__((ext_vector_type(4))) float f32x4;

__device__ __forceinline__ float fdot2(half2_t a, half2_t b, float c) {
#if __has_builtin(__builtin_amdgcn_fdot2)
    return __builtin_amdgcn_fdot2(a, b, c, false);
#else
    return c + (float)a[0] * (float)b[0] + (float)a[1] * (float)b[1];
#endif
}

__device__ __forceinline__ short f2bf(float f) {     // fp32 -> bf16 (RNE)
    unsigned u = __builtin_bit_cast(unsigned, f);
    return (short)((u + 0x7FFFu + ((u >> 16) & 1u)) >> 16);
}

__device__ __forceinline__ void barrier_lds() {
    __asm__ __volatile__("s_waitcnt lgkmcnt(0)" ::: "memory");
    __builtin_amdgcn_s_barrier();
}

// ---------------------------------------------------------------------------
// Kernel 0: pre-swizzle weights into MFMA B-fragment tables.
// G1 (bf16, ff GEMM1): e in [0,8192)
// G2 (bf16, ff GEMM2): e in [8192,24576)
// G3 (f16, rnn W_hh) : e in [24576,40960): ((br*16+nt)*8+ks)*64+lane
// ---------------------------------------------------------------------------
__global__ __launch_bounds__(256, 1)
void prep_kernel(const float* __restrict__ fc11_w, const float* __restrict__ W_ih1,
                 const float* __restrict__ fc21_w, const float* __restrict__ W_ih2,
                 const float* __restrict__ W_hh1, const float* __restrict__ W_hh2,
                 short* __restrict__ tab, _Float16* __restrict__ tab3)
{
    const int e    = blockIdx.x * 256 + threadIdx.x;   // 160*256 = 40960
    const int lane = e & 63;
    const int q = lane >> 4, m = lane & 15;
    if (e < 24576) {
        const float* W;
        int k0, n;
        if (e < 8192) {                       // G1
            int t_ = e >> 6;
            int ks = t_ & 3, nt = (t_ >> 2) & 15, br = t_ >> 6;
            W = br ? fc21_w : fc11_w;
            k0 = ks * 32 + q * 8; n = nt * 16 + m;
        } else {                              // G2
            int t_ = (e - 8192) >> 6;
            int ks = t_ & 7, nt = (t_ >> 3) & 15, br = t_ >> 7;
            W = br ? W_ih2 : W_ih1;
            k0 = ks * 32 + q * 8; n = nt * 16 + m;
        }
        bf16x8 v;
#pragma unroll
        for (int j = 0; j < 8; ++j) v[j] = f2bf(W[(size_t)(k0 + j) * 256 + n]);
        ((bf16x8*)tab)[e] = v;
    } else {                                  // G3: W_hh f16 frags
        int e3 = e - 24576;
        int t_ = e3 >> 6;
        int ks = t_ & 7, nt = (t_ >> 3) & 15, brr = t_ >> 7;
        const float* W = brr ? W_hh2 : W_hh1;
        int k0 = ks * 32 + q * 8, n = nt * 16 + m;
        f16x8 v;
#pragma unroll
        for (int j = 0; j < 8; ++j) v[j] = (_Float16)W[(size_t)(k0 + j) * 256 + n];
        ((f16x8*)tab3)[e3] = v;
    }
}

// ---------------------------------------------------------------------------
// Kernel 1: feed-forward via MFMA. GEMM1 unchanged. GEMM2 epilogue now writes
// pre in the PERMUTED layout (8B packed stores, 32/thread vs 128 scalar).
// ---------------------------------------------------------------------------
__global__ __launch_bounds__(256, 2)
void ff_kernel(const float* __restrict__ state,
               const float* __restrict__ action,
               const float* __restrict__ fc11_b, const float* __restrict__ fc21_b,
               const float* __restrict__ b_hh1, const float* __restrict__ b_ih1,
               const float* __restrict__ b_hh2, const float* __restrict__ b_ih2,
               const short* __restrict__ tab,
               _Float16* __restrict__ pre_out)
{
    __shared__ short X1[128 * 264];

    const int tile = blockIdx.x % 500;
    const int br   = blockIdx.x / 500;
    const int tid  = threadIdx.x;
    const int w    = tid >> 6;
    const int lane = tid & 63;
    const int q = lane >> 4, m = lane & 15;
    const int row0 = tile * 128;

    const float* ba = br ? fc21_b : fc11_b;
    const float* bh = br ? b_hh2 : b_hh1;
    const float* bi = br ? b_ih2 : b_ih1;
    const bf16x8* tG1 = (const bf16x8*)tab + (size_t)br * 4096;
    const bf16x8* tG2 = (const bf16x8*)tab + 8192 + (size_t)br * 8192;

    float ba_v[16], bb_v[16];
#pragma unroll
    for (int nt = 0; nt < 16; ++nt) {
        int c = nt * 16 + m;
        ba_v[nt] = ba[c];
        bb_v[nt] = bh[c] + bi[c];
    }

    // GEMM1 a-frags from global X = concat(state, action)
    bf16x8 af[2][4];
#pragma unroll
    for (int mt = 0; mt < 2; ++mt) {
        const int rw = row0 + 64 * mt + 16 * w + m;
#pragma unroll
        for (int ks = 0; ks < 4; ++ks) {
            int k0 = ks * 32 + q * 8;
            const float* src = (k0 < 96) ? (state  + (size_t)rw * 96 + k0)
                                         : (action + (size_t)rw * 32 + (k0 - 96));
            float4 x0 = *(const float4*)src;
            float4 x1 = *(const float4*)(src + 4);
            bf16x8 a;
            a[0] = f2bf(x0.x); a[1] = f2bf(x0.y); a[2] = f2bf(x0.z); a[3] = f2bf(x0.w);
            a[4] = f2bf(x1.x); a[5] = f2bf(x1.y); a[6] = f2bf(x1.z); a[7] = f2bf(x1.w);
            af[mt][ks] = a;
        }
    }

    // GEMM1: X1 = relu(X @ Wa + ba)
#pragma unroll 4
    for (int nt = 0; nt < 16; ++nt) {
        bf16x8 bf[4];
#pragma unroll
        for (int ks = 0; ks < 4; ++ks) bf[ks] = tG1[(nt * 4 + ks) * 64 + lane];
#pragma unroll
        for (int mt = 0; mt < 2; ++mt) {
            f32x4 acc = {0.f, 0.f, 0.f, 0.f};
#pragma unroll
            for (int ks = 0; ks < 4; ++ks)
                acc = __builtin_amdgcn_mfma_f32_16x16x32_bf16(af[mt][ks], bf[ks], acc, 0, 0, 0);
#pragma unroll
            for (int r = 0; r < 4; ++r) {
                float v = acc[r] + ba_v[nt];
                v = v > 0.f ? v : 0.f;
                X1[(64 * mt + 16 * w + q * 4 + r) * 264 + nt * 16 + m] = f2bf(v);
            }
        }
    }

    // GEMM2 a-frags from LDS (same-wave rows, lgkmcnt suffices)
    bf16x8 a2[2][8];
#pragma unroll
    for (int mt = 0; mt < 2; ++mt)
#pragma unroll
        for (int ks = 0; ks < 8; ++ks)
            a2[mt][ks] = *(const bf16x8*)&X1[(64 * mt + 16 * w + m) * 264 + ks * 32 + q * 8];

    // permuted-store address bases per (mt, r):
    // row -> (b,t); half_base = slab*4096 + (g2*16+m)*16 + rr*4
    size_t hbase[2][4];
#pragma unroll
    for (int mt = 0; mt < 2; ++mt)
#pragma unroll
        for (int r = 0; r < 4; ++r) {
            unsigned row = (unsigned)(row0 + 64 * mt + 16 * w + q * 4 + r);
            unsigned b = row / 1000u;
            unsigned t = row - b * 1000u;
            unsigned G = b >> 4, g2 = (b >> 2) & 3, rr = b & 3;
            hbase[mt][r] = (size_t)(((unsigned)br * 4u + G) * 1000u + t) * 4096u
                         + (size_t)(g2 * 16 + m) * 16u + rr * 4u;
        }

    // GEMM2 grouped by target wave wv (nt = wv*4+tl), packed 8B stores
#pragma unroll
    for (int wv = 0; wv < 4; ++wv) {
        f32x4 accq[2][4];
#pragma unroll
        for (int tl = 0; tl < 4; ++tl) {
            const int nt = wv * 4 + tl;
            bf16x8 bg[8];
#pragma unroll
            for (int ks = 0; ks < 8; ++ks) bg[ks] = tG2[(nt * 8 + ks) * 64 + lane];
#pragma unroll
            for (int mt = 0; mt < 2; ++mt) {
                f32x4 acc = {0.f, 0.f, 0.f, 0.f};
#pragma unroll
                for (int ks = 0; ks < 8; ++ks)
                    acc = __builtin_amdgcn_mfma_f32_16x16x32_bf16(a2[mt][ks], bg[ks], acc, 0, 0, 0);
                accq[mt][tl] = acc;
            }
        }
#pragma unroll
        for (int mt = 0; mt < 2; ++mt)
#pragma unroll
            for (int r = 0; r < 4; ++r) {
                half2_t p0 = {(_Float16)(accq[mt][0][r] + bb_v[wv * 4 + 0]),
                              (_Float16)(accq[mt][1][r] + bb_v[wv * 4 + 1])};
                half2_t p1 = {(_Float16)(accq[mt][2][r] + bb_v[wv * 4 + 2]),
                              (_Float16)(accq[mt][3][r] + bb_v[wv * 4 + 3])};
                uint2 pk = {__builtin_bit_cast(unsigned, p0),
                            __builtin_bit_cast(unsigned, p1)};
                *(uint2*)(pre_out + hbase[mt][r] + (size_t)wv * 1024u) = pk;
            }
    }
}

// ---------------------------------------------------------------------------
// Kernel 2: MFMA recurrence, 16 seqs/block, 8 blocks.
// Per wave: N-slice of 64 cols; W_hh as 32 f16 B-frags (128 VGPRs, pinned).
// Per step: 8 ds_read_b128 (A-frags, conflict-free @528B pitch) + 32 MFMA
// (acc init = pre, so z comes out of the MFMA chain directly) + sigmoid(16)
// + 16 ds_write_b16 + 32B global h store + 32B pre prefetch (t+2). One
// lgkm-only barrier per step. Replaces R3's 128 broadcast LDS reads + 128
// fdot2 critical path (1620 cy/step) with ~450-600 cy.
// ---------------------------------------------------------------------------
__global__ __launch_bounds__(256)
__attribute__((amdgpu_waves_per_eu(1, 1)))
void rnn_kernel(const _Float16* __restrict__ pre_all,
                const float* __restrict__ hn,
                const _Float16* __restrict__ tab3,
                _Float16* __restrict__ h_out)
{
    __shared__ _Float16 hl[2][16][264];   // double-buffered H tile, 528B pitch

    const int wg = blockIdx.x;            // 0..7
    const int br = wg >> 2;
    const int G  = wg & 3;
    const int tid = threadIdx.x;
    const int wv = tid >> 6, l = tid & 63;
    const int g2 = l >> 4, m = l & 15;

    // B-frags for this wave's 64 columns: (tl, ks)
    f16x8 wfr[4][8];
#pragma unroll
    for (int tl = 0; tl < 4; ++tl)
#pragma unroll
        for (int ks = 0; ks < 8; ++ks) {
            const int nt = wv * 4 + tl;
            wfr[tl][ks] = ((const f16x8*)tab3)[(((size_t)br * 16 + nt) * 8 + ks) * 64 + l];
        }
    // PIN: prevent rematerialization of the weight fragments.
#pragma unroll
    for (int tl = 0; tl < 4; ++tl)
#pragma unroll
        for (int ks = 0; ks < 8; ++ks)
            __asm__ __volatile__("" : "+v"(wfr[tl][ks]));

    // init h_lds[0] from hn: thread covers (seq=tid>>4, 16 cols)
    {
        const int seq = tid >> 4, nc = (tid & 15) * 16;
        const float* src = hn + (size_t)(G * 16 + seq) * 256 + nc;
#pragma unroll
        for (int j = 0; j < 16; ++j) hl[0][seq][nc + j] = (_Float16)src[j];
    }
    barrier_lds();

    const size_t slab0 = (size_t)(br * 4 + G) * 1000u;
    f16x16 pc = *(const f16x16*)(pre_all + (slab0 + 0) * 4096u + (size_t)tid * 16u);
    f16x16 pn = *(const f16x16*)(pre_all + (slab0 + 1) * 4096u + (size_t)tid * 16u);

    for (int tt = 0; tt < 1000; ++tt) {
        const int t2 = (tt + 2 < 1000) ? (tt + 2) : 999;
        f16x16 p2 = *(const f16x16*)(pre_all + (slab0 + t2) * 4096u + (size_t)tid * 16u);

        const int pp = tt & 1;

        // A-frags: lane reads h[seq=m][k = ks*32 + g2*8 .. +8]
        f16x8 a[8];
#pragma unroll
        for (int ks = 0; ks < 8; ++ks)
            a[ks] = *(const f16x8*)&hl[pp][m][ks * 32 + g2 * 8];

        // acc init from pre (v = r*4 + tl), then MFMA chain gives z directly
        f32x4 acc[4];
#pragma unroll
        for (int tl = 0; tl < 4; ++tl)
#pragma unroll
            for (int r = 0; r < 4; ++r)
                acc[tl][r] = (float)pc[r * 4 + tl];
#pragma unroll
        for (int ks = 0; ks < 8; ++ks)
#pragma unroll
            for (int tl = 0; tl < 4; ++tl)
                acc[tl] = __builtin_amdgcn_mfma_f32_16x16x32_f16(a[ks], wfr[tl][ks], acc[tl], 0, 0, 0);

        // sigmoid, pack, LDS + global stores
        unsigned hp[8];
#pragma unroll
        for (int r = 0; r < 4; ++r)
#pragma unroll
            for (int tp = 0; tp < 2; ++tp) {
                const int tl0 = 2 * tp;
                float h0 = 1.0f / (1.0f + __expf(-acc[tl0 + 0][r]));
                float h1 = 1.0f / (1.0f + __expf(-acc[tl0 + 1][r]));
                half2_t h2 = {(_Float16)h0, (_Float16)h1};
                hp[r * 2 + tp] = __builtin_bit_cast(unsigned, h2);
                hl[pp ^ 1][g2 * 4 + r][wv * 64 + (tl0 + 0) * 16 + m] = h2[0];
                hl[pp ^ 1][g2 * 4 + r][wv * 64 + (tl0 + 1) * 16 + m] = h2[1];
            }
        _Float16* hgp = h_out + (slab0 + tt) * 4096u + (size_t)tid * 16u;
        *(uint4*)hgp       = uint4{hp[0], hp[1], hp[2], hp[3]};
        *(uint4*)(hgp + 8) = uint4{hp[4], hp[5], hp[6], hp[7]};

        barrier_lds();                    // publish h for step tt+1
        pc = pn; pn = p2;
    }
}

// ---------------------------------------------------------------------------
// Kernel 3: q head on permuted h. One block per slab (br,G,t): 256 threads
// load 8KB, 8 fdot2 each, m-lane shuffle reduce + tiny LDS cross-wave reduce,
// 16 outputs.
// ---------------------------------------------------------------------------
__global__ __launch_bounds__(256, 4)
void q_kernel(const _Float16* __restrict__ h_all,
              const float* __restrict__ fc12_w, const float* __restrict__ fc12_b,
              const float* __restrict__ fc22_w, const float* __restrict__ fc22_b,
              float* __restrict__ out)
{
    __shared__ float part[4][4][4];       // [wv][g2][r]
    const int sb  = blockIdx.x;           // slab = (br*4+G)*1000 + t, 8000 blocks
    const int br  = sb / 4000;
    const int rem = sb - br * 4000;
    const int G   = rem / 1000;
    const int t   = rem - G * 1000;
    const int tid = threadIdx.x;
    const int wv = tid >> 6, l = tid & 63, g2 = l >> 4, m = l & 15;
    const float* qwp = br ? fc22_w : fc12_w;

    f16x16 hv = *(const f16x16*)(h_all + (size_t)sb * 4096u + (size_t)tid * 16u);
    half2_t q01 = {(_Float16)qwp[wv * 64 + 0 * 16 + m], (_Float16)qwp[wv * 64 + 1 * 16 + m]};
    half2_t q23 = {(_Float16)qwp[wv * 64 + 2 * 16 + m], (_Float16)qwp[wv * 64 + 3 * 16 + m]};

    float s0, s1, s2, s3;
    {
        half2_t a0 = {hv[0],  hv[1]},  b0 = {hv[2],  hv[3]};
        half2_t a1 = {hv[4],  hv[5]},  b1 = {hv[6],  hv[7]};
        half2_t a2 = {hv[8],  hv[9]},  b2 = {hv[10], hv[11]};
        half2_t a3 = {hv[12], hv[13]}, b3 = {hv[14], hv[15]};
        s0 = fdot2(b0, q23, fdot2(a0, q01, 0.f));
        s1 = fdot2(b1, q23, fdot2(a1, q01, 0.f));
        s2 = fdot2(b2, q23, fdot2(a2, q01, 0.f));
        s3 = fdot2(b3, q23, fdot2(a3, q01, 0.f));
    }
#pragma unroll
    for (int off = 1; off < 16; off <<= 1) {
        s0 += __shfl_xor(s0, off, 64);
        s1 += __shfl_xor(s1, off, 64);
        s2 += __shfl_xor(s2, off, 64);
        s3 += __shfl_xor(s3, off, 64);
    }
    if (m == 0) *(float4*)&part[wv][g2][0] = float4{s0, s1, s2, s3};
    __syncthreads();
    if (tid < 16) {
        const int gg = tid >> 2, rr = tid & 3;
        float q = (part[0][gg][rr] + part[1][gg][rr]) +
                  (part[2][gg][rr] + part[3][gg][rr]) +
                  (br ? fc22_b[0] : fc12_b[0]);
        out[(size_t)br * 64000u + (size_t)(G * 16 + gg * 4 + rr) * 1000u + t] = q;
    }
}

// ---------------------------------------------------------------------------
extern "C" void kernel_launch(void* const* d_in, const int* in_sizes, int n_in,
                              void* d_out, int out_size, void* d_ws, size_t ws_size,
                              hipStream_t stream)
{
    const float* state  = (const float*)d_in[0];
    const float* action = (const float*)d_in[1];
    const float* hn     = (const float*)d_in[2];
    const float* fc11_w = (const float*)d_in[3];
    const float* fc11_b = (const float*)d_in[4];
    const float* W_hh1  = (const float*)d_in[5];
    const float* W_ih1  = (const float*)d_in[6];
    const float* b_hh1  = (const float*)d_in[7];
    const float* b_ih1  = (const float*)d_in[8];
    const float* fc12_w = (const float*)d_in[9];
    const float* fc12_b = (const float*)d_in[10];
    const float* fc21_w = (const float*)d_in[11];
    const float* fc21_b = (const float*)d_in[12];
    const float* W_hh2  = (const float*)d_in[13];
    const float* W_ih2  = (const float*)d_in[14];
    const float* b_hh2  = (const float*)d_in[15];
    const float* b_ih2  = (const float*)d_in[16];
    const float* fc22_w = (const float*)d_in[17];
    const float* fc22_b = (const float*)d_in[18];

    _Float16* pre  = (_Float16*)d_ws;                          // 65,536,000 B
    _Float16* hbg  = (_Float16*)d_ws + 32768000u;              // 65,536,000 B
    _Float16* tab3 = (_Float16*)((char*)d_ws + 130416640u);    // 262,144 B (h tail)
    short*    tab  = (short*)((char*)d_ws + 130678784u);       // 393,216 B (h tail)

    prep_kernel<<<160, 256, 0, stream>>>(fc11_w, W_ih1, fc21_w, W_ih2,
                                         W_hh1, W_hh2, tab, tab3);
    ff_kernel<<<1000, 256, 0, stream>>>(state, action,
                                        fc11_b, fc21_b, b_hh1, b_ih1,
                                        b_hh2, b_ih2, tab, pre);
    rnn_kernel<<<8, 256, 0, stream>>>(pre, hn, tab3, hbg);
    q_kernel<<<8000, 256, 0, stream>>>(hbg, fc12_w, fc12_b, fc22_w, fc22_b,
                                       (float*)d_out);
}

// Round 5
// 1085.210 us; speedup vs baseline: 1.1407x; 1.1407x over previous
//
#include <hip/hip_runtime.h>
#include <math.h>

// B=64, T=1000, S=96, A=32, INP=128, H=256. All I/O fp32.
// d_ws: pre fp16 [2][64000][256] = 65,536,000 B | h fp16 same = 65,536,000 B.
// W frag tables (393,216 B) live in the TAIL of the h region: ff reads them
// before rnn overwrites that region with h. Total ws use = 131,072,000 B.

typedef _Float16 half2_t __attribute__((ext_vector_type(2)));
typedef __attribute__((ext_vector_type(8))) short bf16x8;   // 8 bf16 in 4 VGPRs
typedef __attribute__((ext_vector_type(4))) float f32x4;

__device__ __forceinline__ float fdot2(half2_t a, half2_t b, float c) {
#if __has_builtin(__builtin_amdgcn_fdot2)
    return __builtin_amdgcn_fdot2(a, b, c, false);   // v_dot2_f32_f16
#else
    return c + (float)a[0] * (float)b[0] + (float)a[1] * (float)b[1];
#endif
}

__device__ __forceinline__ short f2bf(float f) {     // fp32 -> bf16 (RNE)
    unsigned u = __builtin_bit_cast(unsigned, f);
    return (short)((u + 0x7FFFu + ((u >> 16) & 1u)) >> 16);
}

// Barrier WITHOUT the vmcnt(0) drain __syncthreads() inserts. Safe when
// inter-wave communication is LDS-only (lgkmcnt covers DS ops).
__device__ __forceinline__ void barrier_lds() {
    __asm__ __volatile__("s_waitcnt lgkmcnt(0)" ::: "memory");
    __builtin_amdgcn_s_barrier();
}

// ---------------------------------------------------------------------------
// Kernel 0: pre-swizzle W into MFMA B-fragment tables (bf16).
// B-frag for mfma_f32_16x16x32_bf16: lane holds B[k = (lane>>4)*8 + j][n = lane&15]
// G1 entries: ((br*16+nt)*4+ks)*64+lane   (Wa: fc11_w/fc21_w, K=128)
// G2 entries: 8192 + ((br*16+nt)*8+ks)*64+lane (Wi: W_ih1/W_ih2, K=256)
// ---------------------------------------------------------------------------
__global__ __launch_bounds__(256, 1)
void prep_kernel(const float* __restrict__ fc11_w, const float* __restrict__ W_ih1,
                 const float* __restrict__ fc21_w, const float* __restrict__ W_ih2,
                 short* __restrict__ tab)
{
    const int e    = blockIdx.x * 256 + threadIdx.x;   // 96*256 = 24576 entries
    const int lane = e & 63;
    const int q = lane >> 4, m = lane & 15;
    const float* W;
    int k0, n;
    if (e < 8192) {                       // G1
        int t_ = e >> 6;
        int ks = t_ & 3, nt = (t_ >> 2) & 15, br = t_ >> 6;
        W = br ? fc21_w : fc11_w;
        k0 = ks * 32 + q * 8; n = nt * 16 + m;
    } else {                              // G2
        int t_ = (e - 8192) >> 6;
        int ks = t_ & 7, nt = (t_ >> 3) & 15, br = t_ >> 7;
        W = br ? W_ih2 : W_ih1;
        k0 = ks * 32 + q * 8; n = nt * 16 + m;
    }
    bf16x8 v;
#pragma unroll
    for (int j = 0; j < 8; ++j) v[j] = f2bf(W[(size_t)(k0 + j) * 256 + n]);
    ((bf16x8*)tab)[e] = v;
}

// ---------------------------------------------------------------------------
// Kernel 1: feed-forward via MFMA. 128-row blocks (grid 1000, 2 m-tiles per
// wave) — each B-frag load feeds 2 m-tiles, halving L2 b-frag traffic.
// LDS 67.6 KB keeps 2 blocks/CU.
// ---------------------------------------------------------------------------
__global__ __launch_bounds__(256, 2)
void ff_kernel(const float* __restrict__ state,
               const float* __restrict__ action,
               const float* __restrict__ fc11_b, const float* __restrict__ fc21_b,
               const float* __restrict__ b_hh1, const float* __restrict__ b_ih1,
               const float* __restrict__ b_hh2, const float* __restrict__ b_ih2,
               const short* __restrict__ tab,
               _Float16* __restrict__ pre_out)
{
    __shared__ short X1[128 * 264];       // 67.6 KB bf16, +8 pad per row

    const int tile = blockIdx.x % 500;
    const int br   = blockIdx.x / 500;
    const int tid  = threadIdx.x;
    const int w    = tid >> 6;
    const int lane = tid & 63;
    const int q = lane >> 4, m = lane & 15;
    const int row0 = tile * 128;

    const float* ba = br ? fc21_b : fc11_b;
    const float* bh = br ? b_hh2 : b_hh1;
    const float* bi = br ? b_ih2 : b_ih1;
    const bf16x8* tG1 = (const bf16x8*)tab + (size_t)br * 4096;
    const bf16x8* tG2 = (const bf16x8*)tab + 8192 + (size_t)br * 8192;

    // per-lane bias values (col = nt*16 + m)
    float ba_v[16], bb_v[16];
#pragma unroll
    for (int nt = 0; nt < 16; ++nt) {
        int c = nt * 16 + m;
        ba_v[nt] = ba[c];
        bb_v[nt] = bh[c] + bi[c];
    }

    // GEMM1 a-frags from global X = concat(state[96], action[32]), 2 m-tiles
    bf16x8 af[2][4];
#pragma unroll
    for (int mt = 0; mt < 2; ++mt) {
        const int rw = row0 + 64 * mt + 16 * w + m;   // a-frag row of this lane
#pragma unroll
        for (int ks = 0; ks < 4; ++ks) {
            int k0 = ks * 32 + q * 8;
            const float* src = (k0 < 96) ? (state  + (size_t)rw * 96 + k0)
                                         : (action + (size_t)rw * 32 + (k0 - 96));
            float4 x0 = *(const float4*)src;
            float4 x1 = *(const float4*)(src + 4);
            bf16x8 a;
            a[0] = f2bf(x0.x); a[1] = f2bf(x0.y); a[2] = f2bf(x0.z); a[3] = f2bf(x0.w);
            a[4] = f2bf(x1.x); a[5] = f2bf(x1.y); a[6] = f2bf(x1.z); a[7] = f2bf(x1.w);
            af[mt][ks] = a;
        }
    }

    // GEMM1: X1 = relu(X @ Wa + ba); b-frags loaded once per nt, used 2x
#pragma unroll 4
    for (int nt = 0; nt < 16; ++nt) {
        bf16x8 bf[4];
#pragma unroll
        for (int ks = 0; ks < 4; ++ks) bf[ks] = tG1[(nt * 4 + ks) * 64 + lane];
#pragma unroll
        for (int mt = 0; mt < 2; ++mt) {
            f32x4 acc = {0.f, 0.f, 0.f, 0.f};
#pragma unroll
            for (int ks = 0; ks < 4; ++ks)
                acc = __builtin_amdgcn_mfma_f32_16x16x32_bf16(af[mt][ks], bf[ks], acc, 0, 0, 0);
#pragma unroll
            for (int r = 0; r < 4; ++r) {     // D: col=lane&15, row=q*4+r
                float v = acc[r] + ba_v[nt];
                v = v > 0.f ? v : 0.f;
                X1[(64 * mt + 16 * w + q * 4 + r) * 264 + nt * 16 + m] = f2bf(v);
            }
        }
    }
    // X1 rows for m-tiles of wave w are written and read by THIS wave only ->
    // lgkmcnt ordering suffices; no barrier.

    // GEMM2 a-frags from LDS
    bf16x8 a2[2][8];
#pragma unroll
    for (int mt = 0; mt < 2; ++mt)
#pragma unroll
        for (int ks = 0; ks < 8; ++ks)
            a2[mt][ks] = *(const bf16x8*)&X1[(64 * mt + 16 * w + m) * 264 + ks * 32 + q * 8];

    _Float16* pre = pre_out + (size_t)br * 64000u * 256u;
#pragma unroll 2
    for (int nt = 0; nt < 16; ++nt) {
        bf16x8 bg[8];
#pragma unroll
        for (int ks = 0; ks < 8; ++ks) bg[ks] = tG2[(nt * 8 + ks) * 64 + lane];
#pragma unroll
        for (int mt = 0; mt < 2; ++mt) {
            f32x4 acc = {0.f, 0.f, 0.f, 0.f};
#pragma unroll
            for (int ks = 0; ks < 8; ++ks)
                acc = __builtin_amdgcn_mfma_f32_16x16x32_bf16(a2[mt][ks], bg[ks], acc, 0, 0, 0);
#pragma unroll
            for (int r = 0; r < 4; ++r) {
                float v = acc[r] + bb_v[nt];
                pre[(size_t)(row0 + 64 * mt + 16 * w + q * 4 + r) * 256 + nt * 16 + m] = (_Float16)v;
            }
        }
    }
}

// ---------------------------------------------------------------------------
// Kernel 2: recurrence. Structure as R3 (lane owns full column, 1 barrier per
// step, race-free double-buffered hbuf). CHANGES vs R3, from the 4-round
// triangulation (R0/R1/R3 all show ~670 VALU cy/step vs ~310 expected =
// one v_accvgpr_read per weight use; 1 wave/SIMD exposes all latency):
//  1. TLP: 64 blocks x 512 threads = 2 INDEPENDENT sequences per block
//     (waves 0-3 / 4-7) -> 2 waves/SIMD; sibling sequence fills stalls.
//  2. whb re-pinned INSIDE the step loop -> allocator must keep weights in
//     arch VGPRs across iterations (no AGPR park + per-use copy-back).
//  3. tt unrolled x2 with parity-static bodies; pre prefetch loads raw u16
//     into the rotating register (no pc=pn copies -> vmcnt wait sits 2 full
//     steps after the load).
// ---------------------------------------------------------------------------
__global__ __launch_bounds__(512)
__attribute__((amdgpu_waves_per_eu(2, 2)))
void rnn_kernel(const _Float16* __restrict__ pre_all,
                const float* __restrict__ hn,
                const float* __restrict__ W_hh1,
                const float* __restrict__ W_hh2,
                _Float16* __restrict__ h_out)
{
    __shared__ _Float16 hbuf[2][2][256];   // [seq-half][parity][col], 2 KB

    const int tid = threadIdx.x;
    const int sl  = tid >> 8;            // which sequence in this block (wave-uniform)
    const int t   = tid & 255;           // column owned by this thread
    const int s   = blockIdx.x * 2 + sl; // 0..127
    const int br  = s >> 6;
    const int b   = s & 63;
    const float* Whh = br ? W_hh2 : W_hh1;
    const _Float16* pre = pre_all + ((size_t)br * 64000u + (size_t)b * 1000u) * 256u;
    _Float16* hg = h_out + ((size_t)br * 64000u + (size_t)b * 1000u) * 256u;

    // weights: full column t, k in [0,256), half2 pairs (2i, 2i+1) along k.
    // FULLY unrolled, static indices only -> 128 SSA values.
    unsigned whb[128];
#pragma unroll
    for (int i = 0; i < 128; ++i) {
        float lo = Whh[(size_t)(2 * i)     * 256 + t];
        float hi = Whh[(size_t)(2 * i + 1) * 256 + t];
        whb[i] = __builtin_bit_cast(unsigned, half2_t{(_Float16)lo, (_Float16)hi});
    }

    hbuf[sl][0][t] = (_Float16)hn[b * 256 + t];
    barrier_lds();

    // pre values carried as raw bits; cvt at use (2 steps after the load)
    unsigned short pA = *(const unsigned short*)(pre + t);          // step tt
    unsigned short pB = *(const unsigned short*)(pre + 256 + t);    // step tt+1

#define WH(idx) __builtin_bit_cast(half2_t, whb[idx])
#define RSTEP(P, PR, TT, T2)                                                  \
    {                                                                         \
        const float4* hb = (const float4*)&hbuf[sl][P][0];                    \
        float sA0 = 0.f, sA1 = 0.f, sA2 = 0.f, sA3 = 0.f;                     \
        float sB0 = 0.f, sB1 = 0.f, sB2 = 0.f, sB3 = 0.f;                     \
        _Pragma("unroll")                                                     \
        for (int j = 0; j < 32; ++j) {                                        \
            float4 v = hb[j];                   /* 8 halves, broadcast */     \
            const half2_t* hh = (const half2_t*)&v;                           \
            if (j & 1) {                                                      \
                sB0 = fdot2(hh[0], WH(4 * j + 0), sB0);                       \
                sB1 = fdot2(hh[1], WH(4 * j + 1), sB1);                       \
                sB2 = fdot2(hh[2], WH(4 * j + 2), sB2);                       \
                sB3 = fdot2(hh[3], WH(4 * j + 3), sB3);                       \
            } else {                                                          \
                sA0 = fdot2(hh[0], WH(4 * j + 0), sA0);                       \
                sA1 = fdot2(hh[1], WH(4 * j + 1), sA1);                       \
                sA2 = fdot2(hh[2], WH(4 * j + 2), sA2);                       \
                sA3 = fdot2(hh[3], WH(4 * j + 3), sA3);                       \
            }                                                                 \
        }                                                                     \
        const float z = (((sA0 + sA1) + (sA2 + sA3)) +                        \
                         ((sB0 + sB1) + (sB2 + sB3))) +                       \
                        (float)__builtin_bit_cast(_Float16, PR);              \
        PR = *(const unsigned short*)(pre + (size_t)(T2) * 256 + t);          \
        const float h = 1.0f / (1.0f + __expf(-z));                           \
        const _Float16 h16 = (_Float16)h;                                     \
        hbuf[sl][(P) ^ 1][t] = h16;                                           \
        hg[(size_t)(TT) * 256 + t] = h16;   /* in flight across barrier */    \
        barrier_lds();                      /* publish h for next step */     \
    }

    for (int tt = 0; tt < 1000; tt += 2) {
        // re-pin weights each iteration: forces arch-VGPR residency in-loop
#pragma unroll
        for (int i = 0; i < 128; ++i)
            __asm__ __volatile__("" : "+v"(whb[i]));

        const int t2 = (tt + 2 < 1000) ? (tt + 2) : 999;
        RSTEP(0, pA, tt, t2)
        const int t3 = (tt + 3 < 1000) ? (tt + 3) : 999;
        RSTEP(1, pB, tt + 1, t3)
    }
#undef RSTEP
#undef WH
}

// ---------------------------------------------------------------------------
// Kernel 3: q head. q[n] = h[n,:] . qw + qb. One thread per output.
// ---------------------------------------------------------------------------
__global__ __launch_bounds__(256, 2)
void q_kernel(const _Float16* __restrict__ h_all,
              const float* __restrict__ fc12_w, const float* __restrict__ fc12_b,
              const float* __restrict__ fc22_w, const float* __restrict__ fc22_b,
              float* __restrict__ out)
{
    const int n  = blockIdx.x * 256 + threadIdx.x;    // 500 blocks -> n < 128000
    const int br = (n >= 64000);                      // block-uniform
    const float* qwp = br ? fc22_w : fc12_w;
    const float  qb  = br ? fc22_b[0] : fc12_b[0];

    half2_t qw[128];
#pragma unroll
    for (int i = 0; i < 128; ++i)
        qw[i] = half2_t{(_Float16)qwp[2 * i], (_Float16)qwp[2 * i + 1]};

    const float4* hr = (const float4*)(h_all + (size_t)n * 256u);
    float s0 = qb, s1 = 0.f, s2 = 0.f, s3 = 0.f;
#pragma unroll
    for (int k = 0; k < 32; ++k) {
        float4 v = hr[k];
        const half2_t* hh = (const half2_t*)&v;
        s0 = fdot2(hh[0], qw[4 * k + 0], s0);
        s1 = fdot2(hh[1], qw[4 * k + 1], s1);
        s2 = fdot2(hh[2], qw[4 * k + 2], s2);
        s3 = fdot2(hh[3], qw[4 * k + 3], s3);
    }
    out[n] = (s0 + s1) + (s2 + s3);
}

// ---------------------------------------------------------------------------
extern "C" void kernel_launch(void* const* d_in, const int* in_sizes, int n_in,
                              void* d_out, int out_size, void* d_ws, size_t ws_size,
                              hipStream_t stream)
{
    const float* state  = (const float*)d_in[0];
    const float* action = (const float*)d_in[1];
    const float* hn     = (const float*)d_in[2];
    const float* fc11_w = (const float*)d_in[3];
    const float* fc11_b = (const float*)d_in[4];
    const float* W_hh1  = (const float*)d_in[5];
    const float* W_ih1  = (const float*)d_in[6];
    const float* b_hh1  = (const float*)d_in[7];
    const float* b_ih1  = (const float*)d_in[8];
    const float* fc12_w = (const float*)d_in[9];
    const float* fc12_b = (const float*)d_in[10];
    const float* fc21_w = (const float*)d_in[11];
    const float* fc21_b = (const float*)d_in[12];
    const float* W_hh2  = (const float*)d_in[13];
    const float* W_ih2  = (const float*)d_in[14];
    const float* b_hh2  = (const float*)d_in[15];
    const float* b_ih2  = (const float*)d_in[16];
    const float* fc22_w = (const float*)d_in[17];
    const float* fc22_b = (const float*)d_in[18];

    _Float16* pre = (_Float16*)d_ws;                         // 65,536,000 B
    _Float16* hbg = (_Float16*)d_ws + 32768000u;             // 65,536,000 B
    short* tab = (short*)((char*)d_ws + 130678784u);         // frag tables (tail of h region)

    prep_kernel<<<96, 256, 0, stream>>>(fc11_w, W_ih1, fc21_w, W_ih2, tab);
    ff_kernel<<<1000, 256, 0, stream>>>(state, action,
                                        fc11_b, fc21_b, b_hh1, b_ih1,
                                        b_hh2, b_ih2, tab, pre);
    rnn_kernel<<<64, 512, 0, stream>>>(pre, hn, W_hh1, W_hh2, hbg);
    q_kernel<<<500, 256, 0, stream>>>(hbg, fc12_w, fc12_b, fc22_w, fc22_b,
                                      (float*)d_out);
}